// Round 8
// baseline (770.542 us; speedup 1.0000x reference)
//
#include <hip/hip_runtime.h>

// WaveNet residual stack, MFMA bf16. 12 chain launches:
//   per stack: fused6 (d=1..32, contiguous halo in LDS)
//            + pair<64> (d=64,128, strip-staged) + pair<256> (d=256,512).
// Waves own full-o row fragments; g round-trips through wave-private LDS
// scratch (no barrier); 2 barriers per block. Skip GEMMs piggyback (cap 4
// blocks/launch) + small tail. Stream fp32 [b][t][c]; operands bf16.
// R8 fix: residual tap is x[t+d] (tap-1), was wrongly tap-0 in pair kernels.

#define CC    64
#define SCC   256
#define BB    4
#define LL0   8192
#define NBLK  40
#define SKIPN 4096

typedef __attribute__((ext_vector_type(8))) short bf16x8;
typedef __attribute__((ext_vector_type(4))) float f32x4;
typedef unsigned short us;

__device__ __forceinline__ us f2bf(float f) {
    union { float f; unsigned u; } v; v.f = f;
    return (us)((v.u + 0x7FFF + ((v.u >> 16) & 1)) >> 16);
}
__device__ __forceinline__ unsigned pk2(float a, float b) {
    return (unsigned)f2bf(a) | ((unsigned)f2bf(b) << 16);
}
__device__ __forceinline__ uint2 pk4(f32x4 v) {
    return (uint2){pk2(v[0], v[1]), pk2(v[2], v[3])};
}
__device__ __forceinline__ bf16x8 pack8(f32x4 u0, f32x4 u1) {
    bf16x8 r;
    r[0]=(short)f2bf(u0[0]); r[1]=(short)f2bf(u0[1]);
    r[2]=(short)f2bf(u0[2]); r[3]=(short)f2bf(u0[3]);
    r[4]=(short)f2bf(u1[0]); r[5]=(short)f2bf(u1[1]);
    r[6]=(short)f2bf(u1[2]); r[7]=(short)f2bf(u1[3]);
    return r;
}
// fp32 [row][64] LDS word index, 32B-chunk XOR swizzle
__device__ __forceinline__ int sws(int r, int c) {
    return (r << 6) + ((((c >> 3) ^ r) & 7) << 3) + (c & 7);
}
// wave-private bf16 scratch [16 rows][64 c], 16B-chunk XOR swizzle
__device__ __forceinline__ int scb(int s, int chunk) {   // bf16 elem index
    return (s << 6) + (((chunk ^ (s & 7)) & 7) << 3);
}

// ---- merged prep: x transpose [b][c][t]->[b][t][c] + weight bf16 casts ----
__global__ __launch_bounds__(256) void prep_kernel(
    const float* __restrict__ x, float* __restrict__ xt_out,
    const float* __restrict__ dc_w, const float* __restrict__ conv_w,
    const float* __restrict__ skip_w,
    us* __restrict__ wcat, us* __restrict__ cwb, us* __restrict__ swb)
{
    if (blockIdx.x < 512) {
        __shared__ float tile[64][65];
        const int b = blockIdx.x >> 7, t0 = (blockIdx.x & 127) * 64;
        const int tid = threadIdx.x;
        #pragma unroll
        for (int p = 0; p < 4; ++p) {
            const int c = p * 16 + (tid >> 4), j = tid & 15;
            const float4 v = *(const float4*)(x + ((size_t)b * CC + c) * LL0 + t0 + j * 4);
            tile[c][j*4+0]=v.x; tile[c][j*4+1]=v.y; tile[c][j*4+2]=v.z; tile[c][j*4+3]=v.w;
        }
        __syncthreads();
        #pragma unroll
        for (int p = 0; p < 4; ++p) {
            const int r = p * 16 + (tid >> 4), h = tid & 15;
            float4 v = {tile[h*4+0][r], tile[h*4+1][r], tile[h*4+2][r], tile[h*4+3][r]};
            *(float4*)(xt_out + ((size_t)b * LL0 + t0 + r) * CC + h * 4) = v;
        }
        return;
    }
    const int n_sw = NBLK * SCC * CC, n_cw = NBLK * CC * CC, n_wc = NBLK * CC * 128;
    for (int idx = (blockIdx.x - 512) * blockDim.x + threadIdx.x; idx < n_sw;
         idx += 1024 * blockDim.x) {
        swb[idx] = f2bf(skip_w[idx]);
        if (idx < n_cw) cwb[idx] = f2bf(conv_w[idx]);
        if (idx < n_wc) {
            const int i = idx >> 13, o = (idx >> 7) & 63, kk = idx & 127;
            wcat[idx] = f2bf(dc_w[(((i * CC + o) * CC) + (kk & 63)) * 2 + (kk >> 6)]);
        }
    }
}

// ---- skip GEMM body; NW waves/WG, tile = NW*16 time rows ----
template<int NW>
__device__ __forceinline__ void skip_body(
    int e, int blk0,
    const us* __restrict__ g_all, const us* __restrict__ swb,
    const float* __restrict__ skip_b, float* __restrict__ out)
{
    constexpr int ROWS = NW * 16;
    constexpr int TPB = (SKIPN / ROWS) * BB;
    const int tid = threadIdx.x, lane = tid & 63, wv = tid >> 6;
    const int j = blk0 + e / TPB;
    const int id = e % TPB;
    const int tt = id % (SKIPN / ROWS);
    const int b  = id / (SKIPN / ROWS);
    const us* g  = g_all + ((size_t)j * BB + b) * SKIPN * CC;
    const us* sw = swb + (size_t)j * SCC * CC;
    const float* sb = skip_b + j * SCC;
    float* op = out + ((size_t)j * BB + b) * SCC * SKIPN;

    const int trow = tt * ROWS + wv * 16 + (lane & 15);
    bf16x8 a[2];
    a[0] = *(const bf16x8*)(g + (size_t)trow * CC + (lane >> 4) * 8);
    a[1] = *(const bf16x8*)(g + (size_t)trow * CC + 32 + (lane >> 4) * 8);
    const int tstore = tt * ROWS + wv * 16 + ((lane >> 4) << 2);
    #pragma unroll 4
    for (int n = 0; n < 16; ++n) {
        const int sc = n * 16 + (lane & 15);
        const float bias = sb[sc];
        f32x4 acc = (f32x4){bias, bias, bias, bias};
        const us* wrow = sw + sc * CC + (lane >> 4) * 8;
        acc = __builtin_amdgcn_mfma_f32_16x16x32_bf16(a[0], *(const bf16x8*)(wrow), acc, 0, 0, 0);
        acc = __builtin_amdgcn_mfma_f32_16x16x32_bf16(a[1], *(const bf16x8*)(wrow + 32), acc, 0, 0, 0);
        *(float4*)(op + (size_t)sc * SKIPN + tstore) = (float4){acc[0], acc[1], acc[2], acc[3]};
    }
}

// ================= fused d=1..32 kernel (512 threads) =================
// sm: RCAP=160 rows fp32 (40KB); scr: 8 waves x 16x64 bf16 (16KB). 2 bar/block.
__global__ __launch_bounds__(512) void fused6_kernel(
    const float* __restrict__ cur, float* __restrict__ nxt,
    const us* __restrict__ wcat_all, const us* __restrict__ cwb_all,
    const float* __restrict__ db_all, const float* __restrict__ cb_all,
    us* __restrict__ g_all, int blk0, int Lin, int ntiles,
    const us* __restrict__ swb, const float* __restrict__ skip_b,
    float* __restrict__ out, int pb0)
{
    const int wg = blockIdx.x, chain = BB * ntiles;
    if (wg >= chain) { skip_body<8>(wg - chain, pb0, g_all, swb, skip_b, out); return; }

    constexpr int TOUT = 96, R0 = 159, RCAP = 160;
    __shared__ __align__(16) float sm[RCAP * CC];
    __shared__ __align__(16) us  scr[8 * 16 * CC];

    const int tid = threadIdx.x, lane = tid & 63, wv = tid >> 6;
    const int b = wg / ntiles, t0 = (wg % ntiles) * TOUT;
    const float* src = cur + (size_t)b * LL0 * CC;
    const int s = lane & 15, q = lane >> 4;
    us* myscr = scr + wv * (16 * CC);

    // stage R0 stream rows
    for (int base = 0; base < R0; base += 32) {
        const int row = base + (tid >> 4);
        const int h4 = (tid & 15) * 4;
        if (row < R0) {
            int gt = t0 + row; if (gt > Lin - 1) gt = Lin - 1;
            *(f32x4*)(sm + sws(row, h4)) = *(const f32x4*)(src + (size_t)gt * CC + h4);
        }
    }
    __syncthreads();

    int Rcur = R0, Lj = Lin;
    for (int j = 0; j < 6; ++j) {
        const int d = 1 << j;
        const int Rn = Rcur - d;
        Lj -= d;
        const us* wj = wcat_all + (size_t)(blk0 + j) * CC * 128;
        const us* cj = cwb_all + (size_t)(blk0 + j) * CC * CC;
        const float* dbj = db_all + (blk0 + j) * CC;
        const float* cbj = cb_all + (blk0 + j) * CC;
        const int wbase = Lj - SKIPN;
        us* gdst = g_all + ((size_t)(blk0 + j) * BB + b) * SKIPN * CC;

        f32x4 r2[2][4];
        #pragma unroll
        for (int fi = 0; fi < 2; ++fi) {
            const int fg = wv + fi * 8;
            const bool act = fg * 16 < Rn;
            if (act) {
                const int t = fg * 16 + s;
                const int tc = t > Rn - 1 ? Rn - 1 : t;
                // conv fragments: taps at rows tc, tc+d
                bf16x8 af0 = pack8(*(const f32x4*)(sm + sws(tc, q * 8)),
                                   *(const f32x4*)(sm + sws(tc, q * 8 + 4)));
                bf16x8 af1 = pack8(*(const f32x4*)(sm + sws(tc, 32 + q * 8)),
                                   *(const f32x4*)(sm + sws(tc, 36 + q * 8)));
                bf16x8 af2 = pack8(*(const f32x4*)(sm + sws(tc + d, q * 8)),
                                   *(const f32x4*)(sm + sws(tc + d, q * 8 + 4)));
                bf16x8 af3 = pack8(*(const f32x4*)(sm + sws(tc + d, 32 + q * 8)),
                                   *(const f32x4*)(sm + sws(tc + d, 36 + q * 8)));
                #pragma unroll
                for (int n = 0; n < 4; ++n) {
                    const int o0 = n * 16 + q * 4;
                    f32x4 acc = *(const f32x4*)(dbj + o0);
                    const us* wr = wj + (n * 16 + s) * 128 + q * 8;
                    acc = __builtin_amdgcn_mfma_f32_16x16x32_bf16(*(const bf16x8*)(wr),      af0, acc, 0, 0, 0);
                    acc = __builtin_amdgcn_mfma_f32_16x16x32_bf16(*(const bf16x8*)(wr + 32), af1, acc, 0, 0, 0);
                    acc = __builtin_amdgcn_mfma_f32_16x16x32_bf16(*(const bf16x8*)(wr + 64), af2, acc, 0, 0, 0);
                    acc = __builtin_amdgcn_mfma_f32_16x16x32_bf16(*(const bf16x8*)(wr + 96), af3, acc, 0, 0, 0);
                    #pragma unroll
                    for (int r = 0; r < 4; ++r) acc[r] = acc[r] > 0.f ? acc[r] : 0.f;
                    // scratch write (wave-private, no barrier): chunk = o0>>3
                    *(uint2*)(myscr + scb(s, n * 2 + (q >> 1)) + (q & 1) * 4) = pk4(acc);
                }
                // g window store straight from scratch (own rows)
                {
                    const int gt = t0 + t;
                    if (t < Rn && gt >= wbase && gt < Lj) {
                        us* gr = gdst + (size_t)(gt - wbase) * CC;
                        #pragma unroll
                        for (int h = 0; h < 2; ++h) {
                            const int ck = q * 2 + h;
                            *(bf16x8*)(gr + ck * 8) = *(const bf16x8*)(myscr + scb(s, ck));
                        }
                    }
                }
                // 1x1 + residual (reads sm rows <= Rcur-1, stable this phase)
                bf16x8 g0 = *(const bf16x8*)(myscr + scb(s, q));
                bf16x8 g1 = *(const bf16x8*)(myscr + scb(s, 4 + q));
                #pragma unroll
                for (int n = 0; n < 4; ++n) {
                    const int o0 = n * 16 + q * 4;
                    f32x4 r = *(const f32x4*)(cbj + o0);
                    const us* wr = cj + (n * 16 + s) * CC + q * 8;
                    r = __builtin_amdgcn_mfma_f32_16x16x32_bf16(*(const bf16x8*)(wr),      g0, r, 0, 0, 0);
                    r = __builtin_amdgcn_mfma_f32_16x16x32_bf16(*(const bf16x8*)(wr + 32), g1, r, 0, 0, 0);
                    r += *(const f32x4*)(sm + sws(tc + d, o0));
                    r2[fi][n] = r;
                }
            }
        }
        __syncthreads();   // all sm reads done
        #pragma unroll
        for (int fi = 0; fi < 2; ++fi) {
            const int fg = wv + fi * 8;
            const int t = fg * 16 + s;
            if (t < Rn) {
                #pragma unroll
                for (int n = 0; n < 4; ++n)
                    *(f32x4*)(sm + sws(t, n * 16 + q * 4)) = r2[fi][n];
            }
        }
        __syncthreads();   // sm writes visible
        Rcur = Rn;
    }

    // final TOUT rows -> nxt
    float* dst = nxt + (size_t)b * LL0 * CC;
    for (int base = 0; base < TOUT; base += 32) {
        const int row = base + (tid >> 4);
        const int h4 = (tid & 15) * 4;
        const int gt = t0 + row;
        if (row < TOUT && gt < Lj)
            *(float4*)(dst + (size_t)gt * CC + h4) = *(const float4*)(sm + sws(row, h4));
    }
}

// ================= strip-fused pair kernel (256 threads) =================
// blocks (d=D, d=2D). Strips of 32 rows at offsets {0,D,2D,3D}. 2 barriers.
template<int D>
__global__ __launch_bounds__(256) void pair_kernel(
    const float* __restrict__ cur, float* __restrict__ nxt,
    const us* __restrict__ wA, const us* __restrict__ wB,
    const us* __restrict__ cA, const us* __restrict__ cB,
    const float* __restrict__ dbA, const float* __restrict__ dbB,
    const float* __restrict__ cbA, const float* __restrict__ cbB,
    us* __restrict__ gA_out, us* __restrict__ gB_out,
    int Lin, int ntB,
    const us* __restrict__ g_all, const us* __restrict__ swb,
    const float* __restrict__ skip_b, float* __restrict__ out, int pb0)
{
    const int wg = blockIdx.x, chain = BB * ntB;
    if (wg >= chain) { skip_body<4>(wg - chain, pb0, g_all, swb, skip_b, out); return; }

    __shared__ __align__(16) float xs[4 * 32 * CC];   // 4 input strips, 32KB
    __shared__ __align__(16) float ms[2 * 32 * CC];   // mid strips {0,2D}, 16KB
    __shared__ __align__(16) us  scr[4 * 16 * CC];    // wave scratch, 8KB

    const int tid = threadIdx.x, lane = tid & 63, wv = tid >> 6;
    const int b = wg / ntB, T0 = (wg % ntB) * 32;
    const float* src = cur + (size_t)b * LL0 * CC;
    const int s = lane & 15, q = lane >> 4;
    us* myscr = scr + wv * (16 * CC);
    const int LoutA = Lin - D, Lout2 = Lin - 3 * D;

    // stage 4 strips (128 rows)
    #pragma unroll
    for (int p = 0; p < 8; ++p) {
        const int row = p * 16 + (tid >> 4);
        const int st = row >> 5, r = row & 31;
        const int h4 = (tid & 15) * 4;
        int gt = T0 + st * D + r; if (gt > Lin - 1) gt = Lin - 1;
        *(f32x4*)(xs + st * (32 * CC) + sws(r, h4)) =
            *(const f32x4*)(src + (size_t)gt * CC + h4);
    }
    __syncthreads();

    // ---- A phase: mid strips m=0 (waves 0,1), m=1 (waves 2,3) ----
    {
        const int m = wv >> 1, rA = (wv & 1) * 16 + s;
        const int tA = T0 + m * 2 * D + rA;
        const float* x0 = xs + (2 * m) * (32 * CC);
        const float* x1 = xs + (2 * m + 1) * (32 * CC);
        bf16x8 af0 = pack8(*(const f32x4*)(x0 + sws(rA, q * 8)),
                           *(const f32x4*)(x0 + sws(rA, q * 8 + 4)));
        bf16x8 af1 = pack8(*(const f32x4*)(x0 + sws(rA, 32 + q * 8)),
                           *(const f32x4*)(x0 + sws(rA, 36 + q * 8)));
        bf16x8 af2 = pack8(*(const f32x4*)(x1 + sws(rA, q * 8)),
                           *(const f32x4*)(x1 + sws(rA, q * 8 + 4)));
        bf16x8 af3 = pack8(*(const f32x4*)(x1 + sws(rA, 32 + q * 8)),
                           *(const f32x4*)(x1 + sws(rA, 36 + q * 8)));
        #pragma unroll
        for (int n = 0; n < 4; ++n) {
            const int o0 = n * 16 + q * 4;
            f32x4 acc = *(const f32x4*)(dbA + o0);
            const us* wr = wA + (n * 16 + s) * 128 + q * 8;
            acc = __builtin_amdgcn_mfma_f32_16x16x32_bf16(*(const bf16x8*)(wr),      af0, acc, 0, 0, 0);
            acc = __builtin_amdgcn_mfma_f32_16x16x32_bf16(*(const bf16x8*)(wr + 32), af1, acc, 0, 0, 0);
            acc = __builtin_amdgcn_mfma_f32_16x16x32_bf16(*(const bf16x8*)(wr + 64), af2, acc, 0, 0, 0);
            acc = __builtin_amdgcn_mfma_f32_16x16x32_bf16(*(const bf16x8*)(wr + 96), af3, acc, 0, 0, 0);
            #pragma unroll
            for (int r = 0; r < 4; ++r) acc[r] = acc[r] > 0.f ? acc[r] : 0.f;
            *(uint2*)(myscr + scb(s, n * 2 + (q >> 1)) + (q & 1) * 4) = pk4(acc);
        }
        // gA window store: strip0 owns t<ntB*32; strip1 covers the tail
        {
            const int wbA = LoutA - SKIPN;
            const bool own = (m == 0) || (tA >= ntB * 32);
            if (own && tA >= wbA && tA < LoutA) {
                us* gr = gA_out + ((size_t)b * SKIPN + (tA - wbA)) * CC;
                #pragma unroll
                for (int h = 0; h < 2; ++h) {
                    const int ck = q * 2 + h;
                    *(bf16x8*)(gr + ck * 8) = *(const bf16x8*)(myscr + scb(s, ck));
                }
            }
        }
        // 1x1 A + residual (tap-1: input[tA + D] = x1) -> ms[m]
        bf16x8 g0 = *(const bf16x8*)(myscr + scb(s, q));
        bf16x8 g1 = *(const bf16x8*)(myscr + scb(s, 4 + q));
        #pragma unroll
        for (int n = 0; n < 4; ++n) {
            const int o0 = n * 16 + q * 4;
            f32x4 r = *(const f32x4*)(cbA + o0);
            const us* wr = cA + (n * 16 + s) * CC + q * 8;
            r = __builtin_amdgcn_mfma_f32_16x16x32_bf16(*(const bf16x8*)(wr),      g0, r, 0, 0, 0);
            r = __builtin_amdgcn_mfma_f32_16x16x32_bf16(*(const bf16x8*)(wr + 32), g1, r, 0, 0, 0);
            r += *(const f32x4*)(x1 + sws(rA, o0));
            *(f32x4*)(ms + m * (32 * CC) + sws(rA, o0)) = r;
        }
    }
    __syncthreads();

    // ---- B phase: out rows T0..T0+32 (waves 2,3 duplicate, stores gated) ----
    {
        const int rB = (wv & 1) * 16 + s;
        const int tB = T0 + rB;
        const bool lead = wv < 2;
        const float* m0 = ms;
        const float* m1 = ms + 32 * CC;
        bf16x8 af0 = pack8(*(const f32x4*)(m0 + sws(rB, q * 8)),
                           *(const f32x4*)(m0 + sws(rB, q * 8 + 4)));
        bf16x8 af1 = pack8(*(const f32x4*)(m0 + sws(rB, 32 + q * 8)),
                           *(const f32x4*)(m0 + sws(rB, 36 + q * 8)));
        bf16x8 af2 = pack8(*(const f32x4*)(m1 + sws(rB, q * 8)),
                           *(const f32x4*)(m1 + sws(rB, q * 8 + 4)));
        bf16x8 af3 = pack8(*(const f32x4*)(m1 + sws(rB, 32 + q * 8)),
                           *(const f32x4*)(m1 + sws(rB, 36 + q * 8)));
        #pragma unroll
        for (int n = 0; n < 4; ++n) {
            const int o0 = n * 16 + q * 4;
            f32x4 acc = *(const f32x4*)(dbB + o0);
            const us* wr = wB + (n * 16 + s) * 128 + q * 8;
            acc = __builtin_amdgcn_mfma_f32_16x16x32_bf16(*(const bf16x8*)(wr),      af0, acc, 0, 0, 0);
            acc = __builtin_amdgcn_mfma_f32_16x16x32_bf16(*(const bf16x8*)(wr + 32), af1, acc, 0, 0, 0);
            acc = __builtin_amdgcn_mfma_f32_16x16x32_bf16(*(const bf16x8*)(wr + 64), af2, acc, 0, 0, 0);
            acc = __builtin_amdgcn_mfma_f32_16x16x32_bf16(*(const bf16x8*)(wr + 96), af3, acc, 0, 0, 0);
            #pragma unroll
            for (int r = 0; r < 4; ++r) acc[r] = acc[r] > 0.f ? acc[r] : 0.f;
            *(uint2*)(myscr + scb(s, n * 2 + (q >> 1)) + (q & 1) * 4) = pk4(acc);
        }
        {
            const int wbB = Lout2 - SKIPN;
            if (lead && tB >= wbB && tB < Lout2) {
                us* gr = gB_out + ((size_t)b * SKIPN + (tB - wbB)) * CC;
                #pragma unroll
                for (int h = 0; h < 2; ++h) {
                    const int ck = q * 2 + h;
                    *(bf16x8*)(gr + ck * 8) = *(const bf16x8*)(myscr + scb(s, ck));
                }
            }
        }
        // 1x1 B + residual (tap-1: A_out[tB + 2D] = m1)
        bf16x8 g0 = *(const bf16x8*)(myscr + scb(s, q));
        bf16x8 g1 = *(const bf16x8*)(myscr + scb(s, 4 + q));
        float* dst = nxt + (size_t)b * LL0 * CC;
        #pragma unroll
        for (int n = 0; n < 4; ++n) {
            const int o0 = n * 16 + q * 4;
            f32x4 r = *(const f32x4*)(cbB + o0);
            const us* wr = cB + (n * 16 + s) * CC + q * 8;
            r = __builtin_amdgcn_mfma_f32_16x16x32_bf16(*(const bf16x8*)(wr),      g0, r, 0, 0, 0);
            r = __builtin_amdgcn_mfma_f32_16x16x32_bf16(*(const bf16x8*)(wr + 32), g1, r, 0, 0, 0);
            r += *(const f32x4*)(m1 + sws(rB, o0));
            if (lead && tB < Lout2)
                *(f32x4*)(dst + (size_t)tB * CC + o0) = r;
        }
    }
}

__global__ __launch_bounds__(256) void skip_kernel(
    const us* __restrict__ g_all, const us* __restrict__ swb,
    const float* __restrict__ skip_b, float* __restrict__ out, int blk0)
{
    skip_body<4>(blockIdx.x, blk0, g_all, swb, skip_b, out);
}

extern "C" void kernel_launch(void* const* d_in, const int* in_sizes, int n_in,
                              void* d_out, int out_size, void* d_ws, size_t ws_size,
                              hipStream_t stream)
{
    const float* x      = (const float*)d_in[0];
    const float* dc_w   = (const float*)d_in[1];
    const float* dc_b   = (const float*)d_in[2];
    const float* conv_w = (const float*)d_in[3];
    const float* conv_b = (const float*)d_in[4];
    const float* skip_w = (const float*)d_in[5];
    const float* skip_b = (const float*)d_in[6];
    float* out = (float*)d_out;

    char* ws = (char*)d_ws;
    float* bufA = (float*)ws;  ws += (size_t)BB * LL0 * CC * 4;
    float* bufB = (float*)ws;  ws += (size_t)BB * LL0 * CC * 4;
    us* g_all = (us*)ws;       ws += (size_t)NBLK * BB * SKIPN * CC * 2;
    us* wcat  = (us*)ws;       ws += (size_t)NBLK * CC * 128 * 2;
    us* cwb   = (us*)ws;       ws += (size_t)NBLK * CC * CC * 2;
    us* swb   = (us*)ws;       ws += (size_t)NBLK * SCC * CC * 2;

    prep_kernel<<<1536, 256, 0, stream>>>(x, bufA, dc_w, conv_w, skip_w, wcat, cwb, swb);

    float* bufs[2] = {bufA, bufB};
    const size_t GSZ = (size_t)BB * SKIPN * CC;
    int Lc = LL0, blk = 0, q = 0, produced = 0, skipped = 0;
    for (int st = 0; st < 4; ++st) {
        {   // fused d=1..32 (blocks blk..blk+5)
            const int Lout = Lc - 63;
            const int nt = (Lout + 95) / 96;
            int cap = produced - skipped; if (cap > 4) cap = 4;
            fused6_kernel<<<dim3(BB * nt + cap * 128), 512, 0, stream>>>(
                bufs[q & 1], bufs[(q + 1) & 1], wcat, cwb, dc_b, conv_b,
                g_all, blk, Lc, nt, swb, skip_b, out, skipped);
            skipped += cap; produced += 6; blk += 6; Lc = Lout; ++q;
        }
        #pragma unroll
        for (int pi = 0; pi < 2; ++pi) {  // pair<64> then pair<256>
            const int D = pi == 0 ? 64 : 256;
            const int Lout2 = Lc - 3 * D;
            const int nt = (Lout2 + 31) / 32;
            int cap = produced - skipped; if (cap > 4) cap = 4;
            const int grid = BB * nt + cap * 256;
            if (D == 64)
                pair_kernel<64><<<dim3(grid), 256, 0, stream>>>(
                    bufs[q & 1], bufs[(q + 1) & 1],
                    wcat + (size_t)blk * CC * 128, wcat + (size_t)(blk + 1) * CC * 128,
                    cwb + (size_t)blk * CC * CC, cwb + (size_t)(blk + 1) * CC * CC,
                    dc_b + blk * CC, dc_b + (blk + 1) * CC,
                    conv_b + blk * CC, conv_b + (blk + 1) * CC,
                    g_all + (size_t)blk * GSZ, g_all + (size_t)(blk + 1) * GSZ,
                    Lc, nt, g_all, swb, skip_b, out, skipped);
            else
                pair_kernel<256><<<dim3(grid), 256, 0, stream>>>(
                    bufs[q & 1], bufs[(q + 1) & 1],
                    wcat + (size_t)blk * CC * 128, wcat + (size_t)(blk + 1) * CC * 128,
                    cwb + (size_t)blk * CC * CC, cwb + (size_t)(blk + 1) * CC * CC,
                    dc_b + blk * CC, dc_b + (blk + 1) * CC,
                    conv_b + blk * CC, conv_b + (blk + 1) * CC,
                    g_all + (size_t)blk * GSZ, g_all + (size_t)(blk + 1) * GSZ,
                    Lc, nt, g_all, swb, skip_b, out, skipped);
            skipped += cap; produced += 2; blk += 2; Lc = Lout2; ++q;
        }
    }
    const int rem = NBLK - skipped;
    if (rem > 0)
        skip_kernel<<<dim3(rem * 256), 256, 0, stream>>>(g_all, swb, skip_b, out, skipped);
}